// Round 11
// baseline (448.427 us; speedup 1.0000x reference)
//
#include <hip/hip_runtime.h>
#include <math.h>

#define NN 51200
#define EE 1638400
#define GG 512
#define INF 16
#define HCC 128
#define NB 400        // buckets: dst >> 7, 128 nodes each
#define TILE 4096     // edges per k_bin block
#define CSRCAP 4608   // LDS staging capacity in k_csr (bucket avg 4096, max ~4400)
#define NBLK8 (NN / 8) // node-blocks per head-pair phase in k_attn (8 nodes/block)

typedef float vf2 __attribute__((ext_vector_type(2)));
typedef short v8s __attribute__((ext_vector_type(8)));
typedef float v4f __attribute__((ext_vector_type(4)));
typedef int v4i __attribute__((ext_vector_type(4)));
typedef _Float16 vh8 __attribute__((ext_vector_type(8)));
typedef float vf8 __attribute__((ext_vector_type(8)));
#define FMA2 __builtin_elementwise_fma
#define MIN2 __builtin_elementwise_min
#define MAX2 __builtin_elementwise_max
#define NTL(p) __builtin_nontemporal_load(p)

// xl is FP16, PAIR-INTERLEAVED: block p = xl + p*NN*64 (halfs); one node row =
// 128 B = ONE fully-consumed L2 line per gathered edge (r5: FETCH 318->130 MB).
// r10/r11: NON-TEMPORAL hints on all read-once/write-once streams (col, xr, h,
// hin, outr, binned, ei) so they stop evicting the 6.5 MB xl gather set from
// the 4 MB/XCD L2s. xl loads and xl/outl stores stay CACHED (gather-hot).
// NOTE: __builtin_nontemporal_* requires ext_vector_type pointers, NOT
// HIP_vector_type (int4/float4) — hence v4i/v4f aliases (r10 compile fail).
// k_attn: 512-thread blocks, 16-edge events, 1-deep pipeline, DPP reduces;
// structural plateau ~92 us (r1/r4/r6/r7 all <=3%). gbound computed by 100
// parallel blocks fused into k_binlin1 (r9; r8's 1-block version cost 25 us).
// NO online max: scores O(+-10) (glorot), exp safe in fp32, max-sub cancels
// (r2, verified). HARD CONSTRAINT (r1/r4): k_attn VGPR < 64 (m69 cliff).
// lin2 = split-bf16 MFMA GEMM (A_hi*B_hi + A_hi*B_lo + A_lo*B_hi, fp32 acc).

__device__ __forceinline__ int wave_incl_scan(int v, int lane) {
#pragma unroll
    for (int d = 1; d < 64; d <<= 1) {
        int y = __shfl_up(v, d);
        if (lane >= d) v += y;
    }
    return v;
}

__device__ __forceinline__ unsigned short bf16_rtne(float f) {
    unsigned u = __builtin_bit_cast(unsigned, f);
    unsigned r = u + 0x7FFFu + ((u >> 16) & 1u);
    return (unsigned short)(r >> 16);
}

__device__ __forceinline__ unsigned short f16_rtne(float f) {
    return __builtin_bit_cast(unsigned short, (_Float16)f);
}

// DPP lane exchanges (bit-identical value movement to the shfl_xor they replace)
__device__ __forceinline__ float dpp_xor1(float x) {   // quad_perm [1,0,3,2]
    int y = __builtin_amdgcn_mov_dpp(__builtin_bit_cast(int, x), 0xB1, 0xF, 0xF, true);
    return __builtin_bit_cast(float, y);
}
__device__ __forceinline__ float dpp_xor2(float x) {   // quad_perm [2,3,0,1]
    int y = __builtin_amdgcn_mov_dpp(__builtin_bit_cast(int, x), 0x4E, 0xF, 0xF, true);
    return __builtin_bit_cast(float, y);
}
__device__ __forceinline__ float dpp_xor8(float x) {   // row_ror:8 == xor 8 in 16-row
    int y = __builtin_amdgcn_mov_dpp(__builtin_bit_cast(int, x), 0x128, 0xF, 0xF, true);
    return __builtin_bit_cast(float, y);
}

// ---------------- CSR build (binned two-level counting sort) ----------------
__global__ __launch_bounds__(512) void k_hist(const int* __restrict__ ei,
                                              int* __restrict__ bcnt) {
    __shared__ int h[NB];
    int t = threadIdx.x;
    if (t < NB) h[t] = 0;
    __syncthreads();
    const v4i* d4 = (const v4i*)(ei + EE + blockIdx.x * TILE);
#pragma unroll
    for (int s = 0; s < 2; s++) {
        v4i d = NTL(&d4[s * 512 + t]);
        atomicAdd(&h[d.x >> 7], 1);
        atomicAdd(&h[d.y >> 7], 1);
        atomicAdd(&h[d.z >> 7], 1);
        atomicAdd(&h[d.w >> 7], 1);
    }
    __syncthreads();
    if (t < NB && h[t]) atomicAdd(&bcnt[t], h[t]);
}

__global__ __launch_bounds__(512) void k_scan2(const int* __restrict__ bcnt,
                                               int* __restrict__ bbase,
                                               int* __restrict__ gcur,
                                               int* __restrict__ rowptr) {
    __shared__ int sc[512];
    int t = threadIdx.x;
    int v = (t < NB) ? bcnt[t] : 0;
    sc[t] = v;
    __syncthreads();
    for (int off = 1; off < 512; off <<= 1) {
        int u = (t >= off) ? sc[t - off] : 0;
        __syncthreads();
        sc[t] += u;
        __syncthreads();
    }
    if (t < NB) { int ex = sc[t] - v; bbase[t] = ex; gcur[t] = ex; }
    if (t == 0) { bbase[NB] = EE; rowptr[NN] = EE; }
}

// FUSED: blocks [0,NB)                    = tile-local bucket rank -> binned
//        blocks [NB, NB+NN/16)            = layer-1 linear (16 rows each)
//        blocks [NB+NN/16, +8)            = split-bf16 prep of l2 weights
//        blocks [NB+NN/16+8, +NN/512)     = gbound scan (1 thread/node)
__global__ __launch_bounds__(512) void k_binlin1(const int* __restrict__ ei,
                                                 int* __restrict__ gcur,
                                                 unsigned* __restrict__ binned,
                                                 const float* __restrict__ x,
                                                 const float* __restrict__ Wl,
                                                 const float* __restrict__ bl,
                                                 const float* __restrict__ Wr,
                                                 const float* __restrict__ br,
                                                 unsigned short* __restrict__ xl,
                                                 float* __restrict__ xr,
                                                 const float* __restrict__ W2l,
                                                 const float* __restrict__ W2r,
                                                 unsigned short* __restrict__ Bhi,
                                                 unsigned short* __restrict__ Blo,
                                                 const int* __restrict__ batch,
                                                 int* __restrict__ gbound) {
    __shared__ int h[512];
    __shared__ int lexcl[NB], lcur[NB], baseg[NB];
    __shared__ unsigned stage[TILE];
    __shared__ int wsum[8];
    __shared__ float sx[16][INF];
    int t = threadIdx.x;
    if (blockIdx.x < NB) {
        // ---- bin pass ----
        int lane = t & 63, w = t >> 6;
        h[t] = 0;
        __syncthreads();
        int e0 = blockIdx.x * TILE;
        const v4i* s4 = (const v4i*)(ei + e0);
        const v4i* d4 = (const v4i*)(ei + EE + e0);
        int sv[8], dv[8];
#pragma unroll
        for (int q = 0; q < 2; q++) {
            v4i svv = NTL(&s4[q * 512 + t]);
            v4i dvv = NTL(&d4[q * 512 + t]);
            sv[q * 4 + 0] = svv.x; sv[q * 4 + 1] = svv.y;
            sv[q * 4 + 2] = svv.z; sv[q * 4 + 3] = svv.w;
            dv[q * 4 + 0] = dvv.x; dv[q * 4 + 1] = dvv.y;
            dv[q * 4 + 2] = dvv.z; dv[q * 4 + 3] = dvv.w;
            atomicAdd(&h[dvv.x >> 7], 1);
            atomicAdd(&h[dvv.y >> 7], 1);
            atomicAdd(&h[dvv.z >> 7], 1);
            atomicAdd(&h[dvv.w >> 7], 1);
        }
        __syncthreads();
        int myh = h[t];
        int incl = wave_incl_scan(myh, lane);
        if (lane == 63) wsum[w] = incl;
        __syncthreads();
        int woff = 0;
        for (int i = 0; i < w; i++) woff += wsum[i];
        incl += woff;
        if (t < NB) {
            int ex = incl - myh;
            lexcl[t] = ex;
            lcur[t] = ex;
            baseg[t] = atomicAdd(&gcur[t], myh);
        }
        __syncthreads();
#pragma unroll
        for (int s = 0; s < 8; s++) {
            int b = dv[s] >> 7;
            int r = atomicAdd(&lcur[b], 1);
            stage[r] = (unsigned)sv[s] | ((unsigned)dv[s] << 16);
        }
        __syncthreads();
#pragma unroll
        for (int s = 0; s < 8; s++) {
            int idx = s * 512 + t;
            unsigned p = stage[idx];
            int b = (int)(p >> 23);
            binned[baseg[b] + idx - lexcl[b]] = p;
        }
    } else if (blockIdx.x < NB + NN / 16) {
        // ---- layer-1 linear: 16 rows per block ----
        int bid = blockIdx.x - NB;
        int j = t & 127;
        int ty = t >> 7;     // 0..3
        if (t < 256) {
            sx[t >> 4][t & 15] = NTL(&x[(size_t)(bid * 16 + (t >> 4)) * INF + (t & 15)]);
        }
        __syncthreads();
#pragma unroll
        for (int it = 0; it < 4; it++) {
            int rl = it * 4 + ty;
            int row = bid * 16 + rl;
            float al = bl[j], ar = br[j];
#pragma unroll
            for (int k = 0; k < INF; k++) {
                float xv = sx[rl][k];
                al = fmaf(xv, Wl[k * HCC + j], al);
                ar = fmaf(xv, Wr[k * HCC + j], ar);
            }
            int head = j >> 5, ch = j & 31;
            // xl: pair-interleaved fp16 (see header) — stores stay cached
            xl[((size_t)(head >> 1) * NN + row) * 64 + (head & 1) * 32 + ch] = f16_rtne(al);
            // xr: fp32 head-major
            xr[((size_t)head * NN + row) * 32 + ch] = ar;
        }
    } else if (blockIdx.x < NB + NN / 16 + 8) {
        // ---- bf16 split-prep of l2 weights into fragment order ----
        int gt = (blockIdx.x - NB - NN / 16) * 512 + t;   // 0..4095
        int ks = gt >> 10;
        int rem = gt & 1023;
        int nt = rem >> 6;
        int lane = rem & 63;
        int n = nt * 16 + (lane & 15);
        int kbase = ks * 32 + (lane >> 4) * 8;
        const float* src = (n < 128) ? (W2l + n) : (W2r + n - 128);
        unsigned short hi8[8], lo8[8];
#pragma unroll
        for (int j = 0; j < 8; j++) {
            float v = src[(size_t)(kbase + j) * HCC];
            unsigned short hb = bf16_rtne(v);
            float hf = __builtin_bit_cast(float, (unsigned)hb << 16);
            hi8[j] = hb;
            lo8[j] = bf16_rtne(v - hf);
        }
        size_t idx = (size_t)gt * 8;
#pragma unroll
        for (int j = 0; j < 8; j++) { Bhi[idx + j] = hi8[j]; Blo[idx + j] = lo8[j]; }
    } else {
        // ---- gbound: batch sorted; gbound[g] = first node with batch >= g ----
        int n = (blockIdx.x - NB - NN / 16 - 8) * 512 + t;   // one thread per node
        int bn = batch[n];
        int bp = (n == 0) ? -1 : batch[n - 1];
        for (int g = bp + 1; g <= bn; g++) gbound[g] = n;
        if (n == NN - 1) {
            for (int g = bn + 1; g <= GG; g++) gbound[g] = NN;
        }
    }
}

// per-bucket: per-(node,phase) histogram + scan -> rowptr & phase-grouped col.
__global__ __launch_bounds__(512) void k_csr(const unsigned* __restrict__ binned,
                                             const int* __restrict__ bbase,
                                             int* __restrict__ rowptr,
                                             int* __restrict__ col) {
    int b = blockIdx.x;
    int base = bbase[b];
    int cnt = bbase[b + 1] - base;
    __shared__ int nh[1024], ncur[1024];   // [node_local(128)][phase(8)]
    __shared__ unsigned sbin[CSRCAP];
    __shared__ int wsum[8];
    int t = threadIdx.x;
    int lane = t & 63, w = t >> 6;
    nh[t] = 0;
    nh[t + 512] = 0;
    __syncthreads();
    for (int e = t; e < cnt; e += 512) {
        unsigned p = NTL(&binned[base + e]);
        if (e < CSRCAP) sbin[e] = p;
        unsigned src = p & 0xFFFFu;
        int key = (int)(((p >> 16) & 127u) << 3) | (int)(src >> 13);
        atomicAdd(&nh[key], 1);
    }
    __syncthreads();
    int c0 = nh[2 * t], c1 = nh[2 * t + 1];
    int tot = c0 + c1;
    int incl = wave_incl_scan(tot, lane);
    if (lane == 63) wsum[w] = incl;
    __syncthreads();
    int woff = 0;
    for (int i = 0; i < w; i++) woff += wsum[i];
    int tex = incl + woff - tot;
    ncur[2 * t] = base + tex;
    ncur[2 * t + 1] = base + tex + c0;
    if ((t & 3) == 0) rowptr[(b << 7) + (t >> 2)] = base + tex;
    __syncthreads();
    for (int e = t; e < cnt; e += 512) {
        unsigned p = (e < CSRCAP) ? sbin[e] : NTL(&binned[base + e]);
        unsigned src = p & 0xFFFFu;
        int key = (int)(((p >> 16) & 127u) << 3) | (int)(src >> 13);
        int r = atomicAdd(&ncur[key], 1);
        col[r] = (int)src;
    }
}

// ---------------- layer-2 linear: split-bf16 MFMA GEMM ----------------
// outl (gather plane, layer-2 xl) cached stores; outr (streamed) nt stores.
__global__ __launch_bounds__(256) void k_lin2(const float* __restrict__ hin,
                                              const unsigned short* __restrict__ Bhi,
                                              const unsigned short* __restrict__ Blo,
                                              const float* __restrict__ bl,
                                              const float* __restrict__ br,
                                              unsigned short* __restrict__ outl,
                                              float* __restrict__ outr) {
    const int tid = threadIdx.x;
    const int wv = tid >> 6;
    const int lane = tid & 63;
    const int m = lane & 15;
    const int quad = lane >> 4;
    const int r0 = blockIdx.x * 64 + wv * 16;
    const float* arow = hin + (size_t)(r0 + m) * HCC + quad * 8;
    const v8s* bh = (const v8s*)Bhi;
    const v8s* bo = (const v8s*)Blo;

    v4f acc[16];
#pragma unroll
    for (int nt = 0; nt < 16; nt++) acc[nt] = (v4f){0.f, 0.f, 0.f, 0.f};

#pragma unroll
    for (int ks = 0; ks < 4; ks++) {
        const v4f av0 = NTL((const v4f*)(arow + ks * 32));
        const v4f av1 = NTL((const v4f*)(arow + ks * 32 + 4));
        const float af[8] = {av0.x, av0.y, av0.z, av0.w, av1.x, av1.y, av1.z, av1.w};
        v8s ahi, alo;
#pragma unroll
        for (int e = 0; e < 8; e++) {
            unsigned short hb = bf16_rtne(af[e]);
            float hf = __builtin_bit_cast(float, (unsigned)hb << 16);
            ahi[e] = (short)hb;
            alo[e] = (short)bf16_rtne(af[e] - hf);
        }
        const int base = ks * 16 * 64 + lane;
#pragma unroll
        for (int nt = 0; nt < 16; nt++) {
            v8s bhv = bh[base + nt * 64];
            v8s blv = bo[base + nt * 64];
            acc[nt] = __builtin_amdgcn_mfma_f32_16x16x32_bf16(ahi, bhv, acc[nt], 0, 0, 0);
            acc[nt] = __builtin_amdgcn_mfma_f32_16x16x32_bf16(ahi, blv, acc[nt], 0, 0, 0);
            acc[nt] = __builtin_amdgcn_mfma_f32_16x16x32_bf16(alo, bhv, acc[nt], 0, 0, 0);
        }
    }
#pragma unroll
    for (int nt = 0; nt < 16; nt++) {
        int n = nt * 16 + m;
        int c = n & 127;
        float bv = (n < 128) ? bl[c] : br[c];
        if (n < 128) {   // uniform per nt (n<128 <=> nt<8)
            int head = c >> 5, ch = c & 31;
            unsigned short* op = outl + (size_t)(head >> 1) * NN * 64 + (head & 1) * 32 + ch;
#pragma unroll
            for (int r = 0; r < 4; r++) {
                int row = r0 + quad * 4 + r;
                op[(size_t)row * 64] = f16_rtne(acc[nt][r] + bv);
            }
        } else {
            float* op = outr + (size_t)(c >> 5) * NN * 32 + (c & 31);
#pragma unroll
            for (int r = 0; r < 4; r++) {
                int row = r0 + quad * 4 + r;
                __builtin_nontemporal_store(acc[nt][r] + bv, &op[(size_t)row * 32]);
            }
        }
    }
}

// ---------------- GATv2 attention, one wave per (node, head-PAIR) ---------
// 512-thread blocks (8 nodes each); pair-interleaved fp16 gather (CACHED);
// col/xr loads and h stores NON-TEMPORAL (streams must not evict xl from L2).
// 16-edge events, 1-deep event pipeline; DPP reduces (quad xor1/2, row_ror:8).
__global__ __launch_bounds__(512) void k_attn(const int* __restrict__ rowptr,
                                              const int* __restrict__ col,
                                              const unsigned short* __restrict__ xl,
                                              const float* __restrict__ xr,
                                              const float* __restrict__ att,
                                              const float* __restrict__ bias,
                                              float* __restrict__ hout) {
    const int wave = threadIdx.x >> 6;    // 0..7
    const int lane = threadIdx.x & 63;
    const int sub = lane >> 3;
    const int hl = (lane >> 2) & 1;
    const int hq = lane & 3;
    const int pair = blockIdx.x / NBLK8;
    const int n = (blockIdx.x - pair * NBLK8) * 8 + wave;
    const int head = 2 * pair + hl;

    // per-lane gather base (plane + intra-line offset folded once)
    const char* xlq = (const char*)(xl + (size_t)pair * NN * 64)
                      + (unsigned)(hl * 64 + hq * 16);
    const float* xrp = xr + ((size_t)head * NN + n) * 32 + hq * 8;
    const v4f xrv0 = NTL((const v4f*)(xrp));
    const v4f xrv1 = NTL((const v4f*)(xrp + 4));
    const float4 at0 = *(const float4*)(att + head * 32 + hq * 8);
    const float4 at1 = *(const float4*)(att + head * 32 + hq * 8 + 4);
    const float LOG2E = 1.44269504088896340736f;
    const vf2 xr01 = {xrv0.x, xrv0.y}, xr23 = {xrv0.z, xrv0.w};
    const vf2 xr45 = {xrv1.x, xrv1.y}, xr67 = {xrv1.z, xrv1.w};
    // att pre-scaled by log2e: scores in log2 domain, exp -> bare v_exp_f32
    const vf2 at01 = {at0.x * LOG2E, at0.y * LOG2E}, at23 = {at0.z * LOG2E, at0.w * LOG2E};
    const vf2 at45 = {at1.x * LOG2E, at1.y * LOG2E}, at67 = {at1.z * LOG2E, at1.w * LOG2E};
    const vf2 Z2 = {0.f, 0.f}, C2 = {0.2f, 0.2f};

    const int base = rowptr[n];
    const int deg = rowptr[n + 1] - base;

    float l = 0.f;
    vf2 a01 = Z2, a23 = Z2, a45 = Z2, a67 = Z2;

    for (int i0 = 0; i0 < deg; i0 += 64) {
        int mye = 0;
        if (i0 + lane < deg) mye = NTL(&col[base + i0 + lane]);
        const int cnt = min(64, deg - i0);
        const int events = (cnt + 15) >> 4;   // 16 edges per event
        vh8 ca, cb, na{}, nb{};
        {   // prologue: event 0 loads
            const int s0 = __shfl(mye, sub);
            const int s1 = __shfl(mye, 8 + sub);
            ca = *(const vh8*)(xlq + (((unsigned)s0) << 7));
            cb = *(const vh8*)(xlq + (((unsigned)s1) << 7));
        }
        for (int g = 0; g < events; ++g) {
            if (g + 1 < events) {   // wave-uniform branch
                const int s0 = __shfl(mye, 16 * (g + 1) + sub);
                const int s1 = __shfl(mye, 16 * (g + 1) + 8 + sub);
                na = *(const vh8*)(xlq + (((unsigned)s0) << 7));
                nb = *(const vh8*)(xlq + (((unsigned)s1) << 7));
            }
#pragma unroll
            for (int k = 0; k < 2; ++k) {
                const vf8 fv = __builtin_convertvector(k ? cb : ca, vf8);
                const vf2 v01 = {fv[0], fv[1]}, v23 = {fv[2], fv[3]};
                const vf2 v45 = {fv[4], fv[5]}, v67 = {fv[6], fv[7]};
                vf2 e, kk, p2;
                e = v01 + xr01; kk = FMA2(C2, MIN2(e, Z2), MAX2(e, Z2)); p2 = kk * at01;
                e = v23 + xr23; kk = FMA2(C2, MIN2(e, Z2), MAX2(e, Z2)); p2 = FMA2(kk, at23, p2);
                e = v45 + xr45; kk = FMA2(C2, MIN2(e, Z2), MAX2(e, Z2)); p2 = FMA2(kk, at45, p2);
                e = v67 + xr67; kk = FMA2(C2, MIN2(e, Z2), MAX2(e, Z2)); p2 = FMA2(kk, at67, p2);
                float pp = p2.x + p2.y;
                pp += dpp_xor1(pp);
                pp += dpp_xor2(pp);
                if ((16 * g + 8 * k + sub) >= cnt) pp = -INFINITY;
                const float w = __builtin_amdgcn_exp2f(pp);   // exp2(-inf)=0 pads
                l += w;
                const vf2 W = {w, w};
                a01 = FMA2(W, v01, a01);
                a23 = FMA2(W, v23, a23);
                a45 = FMA2(W, v45, a45);
                a67 = FMA2(W, v67, a67);
            }
            ca = na;
            cb = nb;
        }
    }
    l += dpp_xor8(l);
    l += __shfl_xor(l, 16);
    l += __shfl_xor(l, 32);
    float af[8] = {a01.x, a01.y, a23.x, a23.y, a45.x, a45.y, a67.x, a67.y};
#pragma unroll
    for (int i = 0; i < 8; i++) {
        af[i] += dpp_xor8(af[i]);
        af[i] += __shfl_xor(af[i], 16);
        af[i] += __shfl_xor(af[i], 32);
    }
    const float inv = 1.f / (l + 1e-16f);
    if (sub == 0) {
        const float4 b0 = *(const float4*)(bias + head * 32 + hq * 8);
        const float4 b1 = *(const float4*)(bias + head * 32 + hq * 8 + 4);
        v4f o0, o1;
        o0.x = fmaxf(fmaf(af[0], inv, b0.x), 0.f);
        o0.y = fmaxf(fmaf(af[1], inv, b0.y), 0.f);
        o0.z = fmaxf(fmaf(af[2], inv, b0.z), 0.f);
        o0.w = fmaxf(fmaf(af[3], inv, b0.w), 0.f);
        o1.x = fmaxf(fmaf(af[4], inv, b1.x), 0.f);
        o1.y = fmaxf(fmaf(af[5], inv, b1.y), 0.f);
        o1.z = fmaxf(fmaf(af[6], inv, b1.z), 0.f);
        o1.w = fmaxf(fmaf(af[7], inv, b1.w), 0.f);
        float* hp = hout + (size_t)n * HCC + head * 32 + hq * 8;
        __builtin_nontemporal_store(o0, (v4f*)(hp));
        __builtin_nontemporal_store(o1, (v4f*)(hp + 4));
    }
}

// ---------------- pool (precomputed boundaries) + MLP head ----------------
// 256 threads: 2 row-groups read in parallel; combine order (s0+s1)+(s2+s3)
// preserved exactly (bit-identical to the 128-thread version).
__global__ __launch_bounds__(256) void k_head(const float* __restrict__ h,
                                              const int* __restrict__ gbound,
                                              const float* __restrict__ fc1W, const float* __restrict__ fc1b,
                                              const float* __restrict__ bn1g, const float* __restrict__ bn1b,
                                              const float* __restrict__ fc2W, const float* __restrict__ fc2b,
                                              const float* __restrict__ bn2g, const float* __restrict__ bn2b,
                                              const float* __restrict__ fc3W, const float* __restrict__ fc3b,
                                              float* __restrict__ out) {
    int g = blockIdx.x;
    int t = threadIdx.x;
    int j = t & 127;
    int grp = t >> 7;
    __shared__ float buf[HCC], buf2[HCC], part[2][HCC];
    int s = gbound[g];
    int e = gbound[g + 1];
    float p0 = 0.f, p1 = 0.f;
    int n0 = s;
    for (int n = s; n + 3 < e; n += 4) {
        p0 += NTL(&h[(size_t)(n + 2 * grp) * HCC + j]);
        p1 += NTL(&h[(size_t)(n + 2 * grp + 1) * HCC + j]);
        n0 = n + 4;
    }
    if (grp == 0) {
        for (int n = n0; n < e; n++) p0 += NTL(&h[(size_t)n * HCC + j]);
    }
    part[grp][j] = p0 + p1;    // grp0: s0+s1 (incl. remainder in s0); grp1: s2+s3
    __syncthreads();
    float cnt = (float)(e - s);
    if (grp == 0) buf[j] = (part[0][j] + part[1][j]) / fmaxf(cnt, 1.0f);
    __syncthreads();
    const float SQ = 1.00000499998749994f;
    if (grp == 0) {
        float a = fc1b[j];
        for (int k = 0; k < HCC; k++) a = fmaf(buf[k], fc1W[k * HCC + j], a);
        a = fmaf(a, bn1g[j] / SQ, bn1b[j]);
        a = fmaxf(a, 0.f);
        buf2[j] = a;
    }
    __syncthreads();
    if (grp == 0) {
        float a = fc2b[j];
        for (int k = 0; k < HCC; k++) a = fmaf(buf2[k], fc2W[k * HCC + j], a);
        a = fmaf(a, bn2g[j] / SQ, bn2b[j]);
        a = fmaxf(a, 0.f);
        buf[j] = a;
    }
    __syncthreads();
    if (t < 2) {
        float o = fc3b[t];
        for (int k = 0; k < HCC; k++) o = fmaf(buf[k], fc3W[k * 2 + t], o);
        out[g * 2 + t] = o;
    }
}

extern "C" void kernel_launch(void* const* d_in, const int* in_sizes, int n_in,
                              void* d_out, int out_size, void* d_ws, size_t ws_size,
                              hipStream_t stream) {
    const float* x      = (const float*)d_in[0];
    const int*   ei     = (const int*)d_in[1];
    const int*   batch  = (const int*)d_in[2];
    const float* l1_Wl  = (const float*)d_in[3];
    const float* l1_bl  = (const float*)d_in[4];
    const float* l1_Wr  = (const float*)d_in[5];
    const float* l1_br  = (const float*)d_in[6];
    const float* l1_att = (const float*)d_in[7];
    const float* l1_bias= (const float*)d_in[8];
    const float* l2_Wl  = (const float*)d_in[9];
    const float* l2_bl  = (const float*)d_in[10];
    const float* l2_Wr  = (const float*)d_in[11];
    const float* l2_br  = (const float*)d_in[12];
    const float* l2_att = (const float*)d_in[13];
    const float* l2_bias= (const float*)d_in[14];
    const float* fc1_W  = (const float*)d_in[15];
    const float* fc1_b  = (const float*)d_in[16];
    const float* bn1_g  = (const float*)d_in[17];
    const float* bn1_b  = (const float*)d_in[18];
    const float* fc2_W  = (const float*)d_in[19];
    const float* fc2_b  = (const float*)d_in[20];
    const float* bn2_g  = (const float*)d_in[21];
    const float* bn2_b  = (const float*)d_in[22];
    const float* fc3_W  = (const float*)d_in[23];
    const float* fc3_b  = (const float*)d_in[24];
    float* out = (float*)d_out;

    unsigned short* xlh = (unsigned short*)d_ws;          // fp16 pair-interleaved, 13.1 MB
    float* xr = (float*)(xlh + (size_t)NN * HCC);         // fp32, 26.2 MB
    float* h  = xr + (size_t)NN * HCC;                    // fp32, 26.2 MB
    int* rowptr = (int*)(h + (size_t)NN * HCC);
    int* col    = rowptr + (NN + 1);
    int* bcnt   = col + EE;
    int* bbase  = bcnt + NB;
    int* gcur   = bbase + (NB + 1);
    int* gbound = gcur + NB;                              // GG+1 ints
    uintptr_t bp = ((uintptr_t)(gbound + GG + 1) + 15) & ~(uintptr_t)15;
    unsigned short* Bhi = (unsigned short*)bp;       // 64 KB, frag-ordered
    unsigned short* Blo = Bhi + 32768;               // 64 KB
    // binned (6.5 MB) aliases h (26 MB): bin/csr complete before attn1 writes h
    unsigned* binned = (unsigned*)h;

    // CSR build (+ fused layer-1 linear + l2-weight bf16 split-prep + gbound)
    hipMemsetAsync(bcnt, 0, NB * sizeof(int), stream);
    k_hist<<<EE / TILE, 512, 0, stream>>>(ei, bcnt);
    k_scan2<<<1, 512, 0, stream>>>(bcnt, bbase, gcur, rowptr);
    k_binlin1<<<NB + NN / 16 + 8 + NN / 512, 512, 0, stream>>>(
        ei, gcur, binned, x, l1_Wl, l1_bl, l1_Wr, l1_br, xlh, xr,
        l2_Wl, l2_Wr, Bhi, Blo, batch, gbound);
    k_csr<<<NB, 512, 0, stream>>>(binned, bbase, rowptr, col);

    // layer 1 attention (2 head-pair phases, 512-thread blocks)
    k_attn<<<2 * NBLK8, 512, 0, stream>>>(rowptr, col, xlh, xr, l1_att, l1_bias, h);

    // layer 2
    k_lin2<<<NN / 64, 256, 0, stream>>>(h, Bhi, Blo, l2_bl, l2_br, xlh, xr);
    k_attn<<<2 * NBLK8, 512, 0, stream>>>(rowptr, col, xlh, xr, l2_att, l2_bias, h);

    // pool + MLP head
    k_head<<<GG, 256, 0, stream>>>(h, gbound, fc1_W, fc1_b, bn1_g, bn1_b,
                                   fc2_W, fc2_b, bn2_g, bn2_b, fc3_W, fc3_b, out);
}

// Round 12
// 415.748 us; speedup vs baseline: 1.0786x; 1.0786x over previous
//
#include <hip/hip_runtime.h>
#include <math.h>

#define NN 51200
#define EE 1638400
#define GG 512
#define INF 16
#define HCC 128
#define NB 400        // buckets: dst >> 7, 128 nodes each
#define TILE 4096     // edges per k_bin block
#define CSRCAP 4608   // LDS staging capacity in k_csr (bucket avg 4096, max ~4400)
#define NBLK8 (NN / 8) // node-blocks per head-pair phase in k_attn (8 nodes/block)

typedef float vf2 __attribute__((ext_vector_type(2)));
typedef short v8s __attribute__((ext_vector_type(8)));
typedef float v4f __attribute__((ext_vector_type(4)));
typedef _Float16 vh8 __attribute__((ext_vector_type(8)));
typedef float vf8 __attribute__((ext_vector_type(8)));
#define FMA2 __builtin_elementwise_fma
#define MIN2 __builtin_elementwise_min
#define MAX2 __builtin_elementwise_max

// xl is FP16, PAIR-INTERLEAVED: block p = xl + p*NN*64 (halfs); one node row =
// 128 B = ONE fully-consumed L2 line per gathered edge (r5: FETCH 318->130 MB).
// k_attn: 512-thread blocks, 16-edge events, 1-deep pipeline, DPP quad/row
// reduces; structural plateau ~92 us (r1/r4/r6/r7 all <=3%). gbound computed
// by 100 parallel blocks fused into k_binlin1 (r9; r8's 1-block version cost
// 25 us serial). r11 lesson: NO non-temporal hints — every "stream" here is a
// producer->consumer edge through L2 (col read by both pair-phases; xr/h
// written by one kernel, read by the next); NT no-allocate destroyed that
// reuse (FETCH -12% but dur +8%). Classify streams at PIPELINE scope.
// NO online max: scores O(+-10) (glorot), exp safe in fp32, max-sub cancels
// (r2, verified). HARD CONSTRAINT (r1/r4): k_attn VGPR < 64 (m69 cliff).
// lin2 = split-bf16 MFMA GEMM (A_hi*B_hi + A_hi*B_lo + A_lo*B_hi, fp32 acc).

__device__ __forceinline__ int wave_incl_scan(int v, int lane) {
#pragma unroll
    for (int d = 1; d < 64; d <<= 1) {
        int y = __shfl_up(v, d);
        if (lane >= d) v += y;
    }
    return v;
}

__device__ __forceinline__ unsigned short bf16_rtne(float f) {
    unsigned u = __builtin_bit_cast(unsigned, f);
    unsigned r = u + 0x7FFFu + ((u >> 16) & 1u);
    return (unsigned short)(r >> 16);
}

__device__ __forceinline__ unsigned short f16_rtne(float f) {
    return __builtin_bit_cast(unsigned short, (_Float16)f);
}

// DPP lane exchanges (bit-identical value movement to the shfl_xor they replace)
__device__ __forceinline__ float dpp_xor1(float x) {   // quad_perm [1,0,3,2]
    int y = __builtin_amdgcn_mov_dpp(__builtin_bit_cast(int, x), 0xB1, 0xF, 0xF, true);
    return __builtin_bit_cast(float, y);
}
__device__ __forceinline__ float dpp_xor2(float x) {   // quad_perm [2,3,0,1]
    int y = __builtin_amdgcn_mov_dpp(__builtin_bit_cast(int, x), 0x4E, 0xF, 0xF, true);
    return __builtin_bit_cast(float, y);
}
__device__ __forceinline__ float dpp_xor8(float x) {   // row_ror:8 == xor 8 in 16-row
    int y = __builtin_amdgcn_mov_dpp(__builtin_bit_cast(int, x), 0x128, 0xF, 0xF, true);
    return __builtin_bit_cast(float, y);
}

// ---------------- CSR build (binned two-level counting sort) ----------------
__global__ __launch_bounds__(512) void k_hist(const int* __restrict__ ei,
                                              int* __restrict__ bcnt) {
    __shared__ int h[NB];
    int t = threadIdx.x;
    if (t < NB) h[t] = 0;
    __syncthreads();
    int e0 = blockIdx.x * TILE;
#pragma unroll
    for (int s = 0; s < 8; s++) {
        int d = ei[EE + e0 + s * 512 + t];
        atomicAdd(&h[d >> 7], 1);
    }
    __syncthreads();
    if (t < NB && h[t]) atomicAdd(&bcnt[t], h[t]);
}

__global__ __launch_bounds__(512) void k_scan2(const int* __restrict__ bcnt,
                                               int* __restrict__ bbase,
                                               int* __restrict__ gcur,
                                               int* __restrict__ rowptr) {
    __shared__ int sc[512];
    int t = threadIdx.x;
    int v = (t < NB) ? bcnt[t] : 0;
    sc[t] = v;
    __syncthreads();
    for (int off = 1; off < 512; off <<= 1) {
        int u = (t >= off) ? sc[t - off] : 0;
        __syncthreads();
        sc[t] += u;
        __syncthreads();
    }
    if (t < NB) { int ex = sc[t] - v; bbase[t] = ex; gcur[t] = ex; }
    if (t == 0) { bbase[NB] = EE; rowptr[NN] = EE; }
}

// FUSED: blocks [0,NB)                    = tile-local bucket rank -> binned
//        blocks [NB, NB+NN/16)            = layer-1 linear (16 rows each)
//        blocks [NB+NN/16, +8)            = split-bf16 prep of l2 weights
//        blocks [NB+NN/16+8, +NN/512)     = gbound scan (1 thread/node)
__global__ __launch_bounds__(512) void k_binlin1(const int* __restrict__ ei,
                                                 int* __restrict__ gcur,
                                                 unsigned* __restrict__ binned,
                                                 const float* __restrict__ x,
                                                 const float* __restrict__ Wl,
                                                 const float* __restrict__ bl,
                                                 const float* __restrict__ Wr,
                                                 const float* __restrict__ br,
                                                 unsigned short* __restrict__ xl,
                                                 float* __restrict__ xr,
                                                 const float* __restrict__ W2l,
                                                 const float* __restrict__ W2r,
                                                 unsigned short* __restrict__ Bhi,
                                                 unsigned short* __restrict__ Blo,
                                                 const int* __restrict__ batch,
                                                 int* __restrict__ gbound) {
    __shared__ int h[512];
    __shared__ int lexcl[NB], lcur[NB], baseg[NB];
    __shared__ unsigned stage[TILE];
    __shared__ int wsum[8];
    __shared__ float sx[16][INF];
    int t = threadIdx.x;
    if (blockIdx.x < NB) {
        // ---- bin pass ----
        int lane = t & 63, w = t >> 6;
        h[t] = 0;
        __syncthreads();
        int e0 = blockIdx.x * TILE;
        int sv[8], dv[8];
#pragma unroll
        for (int s = 0; s < 8; s++) {
            int e = e0 + s * 512 + t;
            sv[s] = ei[e];
            dv[s] = ei[EE + e];
            atomicAdd(&h[dv[s] >> 7], 1);
        }
        __syncthreads();
        int myh = h[t];
        int incl = wave_incl_scan(myh, lane);
        if (lane == 63) wsum[w] = incl;
        __syncthreads();
        int woff = 0;
        for (int i = 0; i < w; i++) woff += wsum[i];
        incl += woff;
        if (t < NB) {
            int ex = incl - myh;
            lexcl[t] = ex;
            lcur[t] = ex;
            baseg[t] = atomicAdd(&gcur[t], myh);
        }
        __syncthreads();
#pragma unroll
        for (int s = 0; s < 8; s++) {
            int b = dv[s] >> 7;
            int r = atomicAdd(&lcur[b], 1);
            stage[r] = (unsigned)sv[s] | ((unsigned)dv[s] << 16);
        }
        __syncthreads();
#pragma unroll
        for (int s = 0; s < 8; s++) {
            int idx = s * 512 + t;
            unsigned p = stage[idx];
            int b = (int)(p >> 23);
            binned[baseg[b] + idx - lexcl[b]] = p;
        }
    } else if (blockIdx.x < NB + NN / 16) {
        // ---- layer-1 linear: 16 rows per block ----
        int bid = blockIdx.x - NB;
        int j = t & 127;
        int ty = t >> 7;     // 0..3
        if (t < 256) {
            sx[t >> 4][t & 15] = x[(size_t)(bid * 16 + (t >> 4)) * INF + (t & 15)];
        }
        __syncthreads();
#pragma unroll
        for (int it = 0; it < 4; it++) {
            int rl = it * 4 + ty;
            int row = bid * 16 + rl;
            float al = bl[j], ar = br[j];
#pragma unroll
            for (int k = 0; k < INF; k++) {
                float xv = sx[rl][k];
                al = fmaf(xv, Wl[k * HCC + j], al);
                ar = fmaf(xv, Wr[k * HCC + j], ar);
            }
            int head = j >> 5, ch = j & 31;
            // xl: pair-interleaved fp16 (see header)
            xl[((size_t)(head >> 1) * NN + row) * 64 + (head & 1) * 32 + ch] = f16_rtne(al);
            // xr: fp32 head-major
            xr[((size_t)head * NN + row) * 32 + ch] = ar;
        }
    } else if (blockIdx.x < NB + NN / 16 + 8) {
        // ---- bf16 split-prep of l2 weights into fragment order ----
        int gt = (blockIdx.x - NB - NN / 16) * 512 + t;   // 0..4095
        int ks = gt >> 10;
        int rem = gt & 1023;
        int nt = rem >> 6;
        int lane = rem & 63;
        int n = nt * 16 + (lane & 15);
        int kbase = ks * 32 + (lane >> 4) * 8;
        const float* src = (n < 128) ? (W2l + n) : (W2r + n - 128);
        unsigned short hi8[8], lo8[8];
#pragma unroll
        for (int j = 0; j < 8; j++) {
            float v = src[(size_t)(kbase + j) * HCC];
            unsigned short hb = bf16_rtne(v);
            float hf = __builtin_bit_cast(float, (unsigned)hb << 16);
            hi8[j] = hb;
            lo8[j] = bf16_rtne(v - hf);
        }
        size_t idx = (size_t)gt * 8;
#pragma unroll
        for (int j = 0; j < 8; j++) { Bhi[idx + j] = hi8[j]; Blo[idx + j] = lo8[j]; }
    } else {
        // ---- gbound: batch sorted; gbound[g] = first node with batch >= g ----
        int n = (blockIdx.x - NB - NN / 16 - 8) * 512 + t;   // one thread per node
        int bn = batch[n];
        int bp = (n == 0) ? -1 : batch[n - 1];
        for (int g = bp + 1; g <= bn; g++) gbound[g] = n;
        if (n == NN - 1) {
            for (int g = bn + 1; g <= GG; g++) gbound[g] = NN;
        }
    }
}

// per-bucket: per-(node,phase) histogram + scan -> rowptr & phase-grouped col.
__global__ __launch_bounds__(512) void k_csr(const unsigned* __restrict__ binned,
                                             const int* __restrict__ bbase,
                                             int* __restrict__ rowptr,
                                             int* __restrict__ col) {
    int b = blockIdx.x;
    int base = bbase[b];
    int cnt = bbase[b + 1] - base;
    __shared__ int nh[1024], ncur[1024];   // [node_local(128)][phase(8)]
    __shared__ unsigned sbin[CSRCAP];
    __shared__ int wsum[8];
    int t = threadIdx.x;
    int lane = t & 63, w = t >> 6;
    nh[t] = 0;
    nh[t + 512] = 0;
    __syncthreads();
    for (int e = t; e < cnt; e += 512) {
        unsigned p = binned[base + e];
        if (e < CSRCAP) sbin[e] = p;
        unsigned src = p & 0xFFFFu;
        int key = (int)(((p >> 16) & 127u) << 3) | (int)(src >> 13);
        atomicAdd(&nh[key], 1);
    }
    __syncthreads();
    int c0 = nh[2 * t], c1 = nh[2 * t + 1];
    int tot = c0 + c1;
    int incl = wave_incl_scan(tot, lane);
    if (lane == 63) wsum[w] = incl;
    __syncthreads();
    int woff = 0;
    for (int i = 0; i < w; i++) woff += wsum[i];
    int tex = incl + woff - tot;
    ncur[2 * t] = base + tex;
    ncur[2 * t + 1] = base + tex + c0;
    if ((t & 3) == 0) rowptr[(b << 7) + (t >> 2)] = base + tex;
    __syncthreads();
    for (int e = t; e < cnt; e += 512) {
        unsigned p = (e < CSRCAP) ? sbin[e] : binned[base + e];
        unsigned src = p & 0xFFFFu;
        int key = (int)(((p >> 16) & 127u) << 3) | (int)(src >> 13);
        int r = atomicAdd(&ncur[key], 1);
        col[r] = (int)src;
    }
}

// ---------------- layer-2 linear: split-bf16 MFMA GEMM ----------------
// outl (gather plane, layer-2 xl) written fp16 pair-interleaved; outr fp32.
__global__ __launch_bounds__(256) void k_lin2(const float* __restrict__ hin,
                                              const unsigned short* __restrict__ Bhi,
                                              const unsigned short* __restrict__ Blo,
                                              const float* __restrict__ bl,
                                              const float* __restrict__ br,
                                              unsigned short* __restrict__ outl,
                                              float* __restrict__ outr) {
    const int tid = threadIdx.x;
    const int wv = tid >> 6;
    const int lane = tid & 63;
    const int m = lane & 15;
    const int quad = lane >> 4;
    const int r0 = blockIdx.x * 64 + wv * 16;
    const float* arow = hin + (size_t)(r0 + m) * HCC + quad * 8;
    const v8s* bh = (const v8s*)Bhi;
    const v8s* bo = (const v8s*)Blo;

    v4f acc[16];
#pragma unroll
    for (int nt = 0; nt < 16; nt++) acc[nt] = (v4f){0.f, 0.f, 0.f, 0.f};

#pragma unroll
    for (int ks = 0; ks < 4; ks++) {
        const float4 av0 = *(const float4*)(arow + ks * 32);
        const float4 av1 = *(const float4*)(arow + ks * 32 + 4);
        const float af[8] = {av0.x, av0.y, av0.z, av0.w, av1.x, av1.y, av1.z, av1.w};
        v8s ahi, alo;
#pragma unroll
        for (int e = 0; e < 8; e++) {
            unsigned short hb = bf16_rtne(af[e]);
            float hf = __builtin_bit_cast(float, (unsigned)hb << 16);
            ahi[e] = (short)hb;
            alo[e] = (short)bf16_rtne(af[e] - hf);
        }
        const int base = ks * 16 * 64 + lane;
#pragma unroll
        for (int nt = 0; nt < 16; nt++) {
            v8s bhv = bh[base + nt * 64];
            v8s blv = bo[base + nt * 64];
            acc[nt] = __builtin_amdgcn_mfma_f32_16x16x32_bf16(ahi, bhv, acc[nt], 0, 0, 0);
            acc[nt] = __builtin_amdgcn_mfma_f32_16x16x32_bf16(ahi, blv, acc[nt], 0, 0, 0);
            acc[nt] = __builtin_amdgcn_mfma_f32_16x16x32_bf16(alo, bhv, acc[nt], 0, 0, 0);
        }
    }
#pragma unroll
    for (int nt = 0; nt < 16; nt++) {
        int n = nt * 16 + m;
        int c = n & 127;
        float bv = (n < 128) ? bl[c] : br[c];
        if (n < 128) {   // uniform per nt (n<128 <=> nt<8)
            int head = c >> 5, ch = c & 31;
            unsigned short* op = outl + (size_t)(head >> 1) * NN * 64 + (head & 1) * 32 + ch;
#pragma unroll
            for (int r = 0; r < 4; r++) {
                int row = r0 + quad * 4 + r;
                op[(size_t)row * 64] = f16_rtne(acc[nt][r] + bv);
            }
        } else {
            float* op = outr + (size_t)(c >> 5) * NN * 32 + (c & 31);
#pragma unroll
            for (int r = 0; r < 4; r++) {
                int row = r0 + quad * 4 + r;
                op[(size_t)row * 32] = acc[nt][r] + bv;
            }
        }
    }
}

// ---------------- GATv2 attention, one wave per (node, head-PAIR) ---------
// 512-thread blocks (8 nodes each); pair-interleaved fp16 gather; 16-edge
// events, 1-deep event pipeline; DPP reduces (quad xor1/2, row_ror:8).
__global__ __launch_bounds__(512) void k_attn(const int* __restrict__ rowptr,
                                              const int* __restrict__ col,
                                              const unsigned short* __restrict__ xl,
                                              const float* __restrict__ xr,
                                              const float* __restrict__ att,
                                              const float* __restrict__ bias,
                                              float* __restrict__ hout) {
    const int wave = threadIdx.x >> 6;    // 0..7
    const int lane = threadIdx.x & 63;
    const int sub = lane >> 3;
    const int hl = (lane >> 2) & 1;
    const int hq = lane & 3;
    const int pair = blockIdx.x / NBLK8;
    const int n = (blockIdx.x - pair * NBLK8) * 8 + wave;
    const int head = 2 * pair + hl;

    // per-lane gather base (plane + intra-line offset folded once)
    const char* xlq = (const char*)(xl + (size_t)pair * NN * 64)
                      + (unsigned)(hl * 64 + hq * 16);
    const float* xrp = xr + ((size_t)head * NN + n) * 32 + hq * 8;
    const float4 xrv0 = *(const float4*)(xrp);
    const float4 xrv1 = *(const float4*)(xrp + 4);
    const float4 at0 = *(const float4*)(att + head * 32 + hq * 8);
    const float4 at1 = *(const float4*)(att + head * 32 + hq * 8 + 4);
    const float LOG2E = 1.44269504088896340736f;
    const vf2 xr01 = {xrv0.x, xrv0.y}, xr23 = {xrv0.z, xrv0.w};
    const vf2 xr45 = {xrv1.x, xrv1.y}, xr67 = {xrv1.z, xrv1.w};
    // att pre-scaled by log2e: scores in log2 domain, exp -> bare v_exp_f32
    const vf2 at01 = {at0.x * LOG2E, at0.y * LOG2E}, at23 = {at0.z * LOG2E, at0.w * LOG2E};
    const vf2 at45 = {at1.x * LOG2E, at1.y * LOG2E}, at67 = {at1.z * LOG2E, at1.w * LOG2E};
    const vf2 Z2 = {0.f, 0.f}, C2 = {0.2f, 0.2f};

    const int base = rowptr[n];
    const int deg = rowptr[n + 1] - base;

    float l = 0.f;
    vf2 a01 = Z2, a23 = Z2, a45 = Z2, a67 = Z2;

    for (int i0 = 0; i0 < deg; i0 += 64) {
        int mye = 0;
        if (i0 + lane < deg) mye = col[base + i0 + lane];
        const int cnt = min(64, deg - i0);
        const int events = (cnt + 15) >> 4;   // 16 edges per event
        vh8 ca, cb, na{}, nb{};
        {   // prologue: event 0 loads
            const int s0 = __shfl(mye, sub);
            const int s1 = __shfl(mye, 8 + sub);
            ca = *(const vh8*)(xlq + (((unsigned)s0) << 7));
            cb = *(const vh8*)(xlq + (((unsigned)s1) << 7));
        }
        for (int g = 0; g < events; ++g) {
            if (g + 1 < events) {   // wave-uniform branch
                const int s0 = __shfl(mye, 16 * (g + 1) + sub);
                const int s1 = __shfl(mye, 16 * (g + 1) + 8 + sub);
                na = *(const vh8*)(xlq + (((unsigned)s0) << 7));
                nb = *(const vh8*)(xlq + (((unsigned)s1) << 7));
            }
#pragma unroll
            for (int k = 0; k < 2; ++k) {
                const vf8 fv = __builtin_convertvector(k ? cb : ca, vf8);
                const vf2 v01 = {fv[0], fv[1]}, v23 = {fv[2], fv[3]};
                const vf2 v45 = {fv[4], fv[5]}, v67 = {fv[6], fv[7]};
                vf2 e, kk, p2;
                e = v01 + xr01; kk = FMA2(C2, MIN2(e, Z2), MAX2(e, Z2)); p2 = kk * at01;
                e = v23 + xr23; kk = FMA2(C2, MIN2(e, Z2), MAX2(e, Z2)); p2 = FMA2(kk, at23, p2);
                e = v45 + xr45; kk = FMA2(C2, MIN2(e, Z2), MAX2(e, Z2)); p2 = FMA2(kk, at45, p2);
                e = v67 + xr67; kk = FMA2(C2, MIN2(e, Z2), MAX2(e, Z2)); p2 = FMA2(kk, at67, p2);
                float pp = p2.x + p2.y;
                pp += dpp_xor1(pp);
                pp += dpp_xor2(pp);
                if ((16 * g + 8 * k + sub) >= cnt) pp = -INFINITY;
                const float w = __builtin_amdgcn_exp2f(pp);   // exp2(-inf)=0 pads
                l += w;
                const vf2 W = {w, w};
                a01 = FMA2(W, v01, a01);
                a23 = FMA2(W, v23, a23);
                a45 = FMA2(W, v45, a45);
                a67 = FMA2(W, v67, a67);
            }
            ca = na;
            cb = nb;
        }
    }
    l += dpp_xor8(l);
    l += __shfl_xor(l, 16);
    l += __shfl_xor(l, 32);
    float af[8] = {a01.x, a01.y, a23.x, a23.y, a45.x, a45.y, a67.x, a67.y};
#pragma unroll
    for (int i = 0; i < 8; i++) {
        af[i] += dpp_xor8(af[i]);
        af[i] += __shfl_xor(af[i], 16);
        af[i] += __shfl_xor(af[i], 32);
    }
    const float inv = 1.f / (l + 1e-16f);
    if (sub == 0) {
        const float4 b0 = *(const float4*)(bias + head * 32 + hq * 8);
        const float4 b1 = *(const float4*)(bias + head * 32 + hq * 8 + 4);
        float4 o0, o1;
        o0.x = fmaxf(fmaf(af[0], inv, b0.x), 0.f);
        o0.y = fmaxf(fmaf(af[1], inv, b0.y), 0.f);
        o0.z = fmaxf(fmaf(af[2], inv, b0.z), 0.f);
        o0.w = fmaxf(fmaf(af[3], inv, b0.w), 0.f);
        o1.x = fmaxf(fmaf(af[4], inv, b1.x), 0.f);
        o1.y = fmaxf(fmaf(af[5], inv, b1.y), 0.f);
        o1.z = fmaxf(fmaf(af[6], inv, b1.z), 0.f);
        o1.w = fmaxf(fmaf(af[7], inv, b1.w), 0.f);
        float* hp = hout + (size_t)n * HCC + head * 32 + hq * 8;
        *(float4*)(hp) = o0;
        *(float4*)(hp + 4) = o1;
    }
}

// ---------------- pool (precomputed boundaries) + MLP head ----------------
__global__ __launch_bounds__(128) void k_head(const float* __restrict__ h,
                                              const int* __restrict__ gbound,
                                              const float* __restrict__ fc1W, const float* __restrict__ fc1b,
                                              const float* __restrict__ bn1g, const float* __restrict__ bn1b,
                                              const float* __restrict__ fc2W, const float* __restrict__ fc2b,
                                              const float* __restrict__ bn2g, const float* __restrict__ bn2b,
                                              const float* __restrict__ fc3W, const float* __restrict__ fc3b,
                                              float* __restrict__ out) {
    int g = blockIdx.x;
    int j = threadIdx.x;
    __shared__ float buf[HCC], buf2[HCC];
    int s = gbound[g];
    int e = gbound[g + 1];
    float s0 = 0.f, s1 = 0.f, s2 = 0.f, s3 = 0.f;
    int n = s;
    for (; n + 3 < e; n += 4) {
        s0 += h[(size_t)n * HCC + j];
        s1 += h[(size_t)(n + 1) * HCC + j];
        s2 += h[(size_t)(n + 2) * HCC + j];
        s3 += h[(size_t)(n + 3) * HCC + j];
    }
    for (; n < e; n++) s0 += h[(size_t)n * HCC + j];
    float sum = (s0 + s1) + (s2 + s3);
    float cnt = (float)(e - s);
    buf[j] = sum / fmaxf(cnt, 1.0f);
    __syncthreads();
    const float SQ = 1.00000499998749994f;
    float a = fc1b[j];
    for (int k = 0; k < HCC; k++) a = fmaf(buf[k], fc1W[k * HCC + j], a);
    a = fmaf(a, bn1g[j] / SQ, bn1b[j]);
    a = fmaxf(a, 0.f);
    buf2[j] = a;
    __syncthreads();
    a = fc2b[j];
    for (int k = 0; k < HCC; k++) a = fmaf(buf2[k], fc2W[k * HCC + j], a);
    a = fmaf(a, bn2g[j] / SQ, bn2b[j]);
    a = fmaxf(a, 0.f);
    buf[j] = a;
    __syncthreads();
    if (j < 2) {
        float o = fc3b[j];
        for (int k = 0; k < HCC; k++) o = fmaf(buf[k], fc3W[k * 2 + j], o);
        out[g * 2 + j] = o;
    }
}

extern "C" void kernel_launch(void* const* d_in, const int* in_sizes, int n_in,
                              void* d_out, int out_size, void* d_ws, size_t ws_size,
                              hipStream_t stream) {
    const float* x      = (const float*)d_in[0];
    const int*   ei     = (const int*)d_in[1];
    const int*   batch  = (const int*)d_in[2];
    const float* l1_Wl  = (const float*)d_in[3];
    const float* l1_bl  = (const float*)d_in[4];
    const float* l1_Wr  = (const float*)d_in[5];
    const float* l1_br  = (const float*)d_in[6];
    const float* l1_att = (const float*)d_in[7];
    const float* l1_bias= (const float*)d_in[8];
    const float* l2_Wl  = (const float*)d_in[9];
    const float* l2_bl  = (const float*)d_in[10];
    const float* l2_Wr  = (const float*)d_in[11];
    const float* l2_br  = (const float*)d_in[12];
    const float* l2_att = (const float*)d_in[13];
    const float* l2_bias= (const float*)d_in[14];
    const float* fc1_W  = (const float*)d_in[15];
    const float* fc1_b  = (const float*)d_in[16];
    const float* bn1_g  = (const float*)d_in[17];
    const float* bn1_b  = (const float*)d_in[18];
    const float* fc2_W  = (const float*)d_in[19];
    const float* fc2_b  = (const float*)d_in[20];
    const float* bn2_g  = (const float*)d_in[21];
    const float* bn2_b  = (const float*)d_in[22];
    const float* fc3_W  = (const float*)d_in[23];
    const float* fc3_b  = (const float*)d_in[24];
    float* out = (float*)d_out;

    unsigned short* xlh = (unsigned short*)d_ws;          // fp16 pair-interleaved, 13.1 MB
    float* xr = (float*)(xlh + (size_t)NN * HCC);         // fp32, 26.2 MB
    float* h  = xr + (size_t)NN * HCC;                    // fp32, 26.2 MB
    int* rowptr = (int*)(h + (size_t)NN * HCC);
    int* col    = rowptr + (NN + 1);
    int* bcnt   = col + EE;
    int* bbase  = bcnt + NB;
    int* gcur   = bbase + (NB + 1);
    int* gbound = gcur + NB;                              // GG+1 ints
    uintptr_t bp = ((uintptr_t)(gbound + GG + 1) + 15) & ~(uintptr_t)15;
    unsigned short* Bhi = (unsigned short*)bp;       // 64 KB, frag-ordered
    unsigned short* Blo = Bhi + 32768;               // 64 KB
    // binned (6.5 MB) aliases h (26 MB): bin/csr complete before attn1 writes h
    unsigned* binned = (unsigned*)h;

    // CSR build (+ fused layer-1 linear + l2-weight bf16 split-prep + gbound)
    hipMemsetAsync(bcnt, 0, NB * sizeof(int), stream);
    k_hist<<<EE / TILE, 512, 0, stream>>>(ei, bcnt);
    k_scan2<<<1, 512, 0, stream>>>(bcnt, bbase, gcur, rowptr);
    k_binlin1<<<NB + NN / 16 + 8 + NN / 512, 512, 0, stream>>>(
        ei, gcur, binned, x, l1_Wl, l1_bl, l1_Wr, l1_br, xlh, xr,
        l2_Wl, l2_Wr, Bhi, Blo, batch, gbound);
    k_csr<<<NB, 512, 0, stream>>>(binned, bbase, rowptr, col);

    // layer 1 attention (2 head-pair phases, 512-thread blocks)
    k_attn<<<2 * NBLK8, 512, 0, stream>>>(rowptr, col, xlh, xr, l1_att, l1_bias, h);

    // layer 2
    k_lin2<<<NN / 64, 256, 0, stream>>>(h, Bhi, Blo, l2_bl, l2_br, xlh, xr);
    k_attn<<<2 * NBLK8, 512, 0, stream>>>(rowptr, col, xlh, xr, l2_att, l2_bias, h);

    // pool + MLP head
    k_head<<<GG, 128, 0, stream>>>(h, gbound, fc1_W, fc1_b, bn1_g, bn1_b,
                                   fc2_W, fc2_b, bn2_g, bn2_b, fc3_W, fc3_b, out);
}